// Round 3
// baseline (245.584 us; speedup 1.0000x reference)
//
#include <hip/hip_runtime.h>
#include <math.h>

#define AB 128   // A == B == 128
#define NN 64    // N
#define HD 1024  // H
#define TSTRIDE 130  // LDS row stride for T (pad 128 -> 130: all DS access 2-way = free)

// ---------------------------------------------------------------------------
// ws layout (floats):
//   [0, 8192)      FYt transposed: FYt[a][n], a in [0,128), n in [0,64)
//   [8192, 16384)  FXt transposed: FXt[b][m], b in [0,128), m in [0,64)
//   [16384]        gamma
// ---------------------------------------------------------------------------

__device__ __forceinline__ float wave_reduce(float v) {
  v += __shfl_down(v, 32);
  v += __shfl_down(v, 16);
  v += __shfl_down(v, 8);
  v += __shfl_down(v, 4);
  v += __shfl_down(v, 2);
  v += __shfl_down(v, 1);
  return v;  // valid in lane 0
}

// 1024 threads, 1 block. Shuffle-based reductions (few barriers).
__global__ __launch_bounds__(1024) void fb_setup(
    const float* __restrict__ h, const float* __restrict__ Ww,
    const float* __restrict__ Wb, float* __restrict__ ws) {
  __shared__ float redp[16][5];   // per-wave partials for params
  __shared__ float reds[16][2];   // per-wave partials for sums
  __shared__ float sc[5];
  __shared__ float ssum[2];
  const int tid = threadIdx.x;
  const int lane = tid & 63;
  const int wv = tid >> 6;  // 16 waves

  // ---- params[j] = dot(h[0,:], W[j,:]) + b[j] ----
  const float hv = h[tid];  // HD == 1024 == blockDim
  float p[5];
#pragma unroll
  for (int j = 0; j < 5; ++j) p[j] = hv * Ww[j * HD + tid];
#pragma unroll
  for (int j = 0; j < 5; ++j) {
    float r = wave_reduce(p[j]);
    if (lane == 0) redp[wv][j] = r;
  }
  __syncthreads();
  if (tid < 5) {
    float s = Wb[tid];
#pragma unroll
    for (int w = 0; w < 16; ++w) s += redp[w][tid];
    sc[tid] = s;
  }
  __syncthreads();

  const float gt_X = sc[0], gt_Y = sc[1], log_var = sc[2], log_dt = sc[3];
  const float var = expf(log_var + 1e-8f);
  const float g_X = (129.0f * (gt_X + 1.0f)) / 2.0f;
  const float g_Y = (129.0f * (gt_Y + 1.0f)) / 2.0f;
  const float d = (expf(log_dt) * 127.0f) / 63.0f;
  const float twovar = 2.0f * var;

  // ---- filterbank values: 8 per thread each, kept in registers ----
  float fyv[8], fxv[8];
  float sY = 0.f, sX = 0.f;
#pragma unroll
  for (int c = 0; c < 8; ++c) {
    const int idx = tid + 1024 * c;
    const int n = idx >> 7;
    const int col = idx & 127;
    const float idxn = (float)n - 32.5f;
    const float muX = g_X + idxn * d;
    const float muY = g_Y + idxn * d;
    const float dx = (float)col - muX;
    const float dy = (float)col - muY;
    const float fx = expf(-(dx * dx) / twovar);
    const float fy = expf(-(dy * dy) / twovar);
    fyv[c] = fy;
    fxv[c] = fx;
    sY += fy;
    sX += fx;
  }
  {
    float rY = wave_reduce(sY);
    float rX = wave_reduce(sX);
    if (lane == 0) { reds[wv][0] = rY; reds[wv][1] = rX; }
  }
  __syncthreads();
  if (tid < 2) {
    float s = 0.f;
#pragma unroll
    for (int w = 0; w < 16; ++w) s += reds[w][tid];
    ssum[tid] = s;
  }
  __syncthreads();
  const float invY = 1.0f / ssum[0];
  const float invX = 1.0f / ssum[1];
#pragma unroll
  for (int c = 0; c < 8; ++c) {
    const int idx = tid + 1024 * c;
    const int n = idx >> 7;
    const int col = idx & 127;
    ws[col * NN + n] = fyv[c] * invY;             // FYt[a=col][n]
    ws[8192 + col * NN + n] = fxv[c] * invX;      // FXt[b=col][m]
  }
  if (tid == 0) ws[16384] = expf(sc[4]);
}

// ---------------------------------------------------------------------------
// One block per image Z. 512 threads = 8 waves. __launch_bounds__(512,8)
// forces <=64 VGPR so 8 waves/SIMD fit -> 4 blocks/CU = 32 waves = 100% occ.
// Stage 1: wave w owns T rows 8w..8w+7; lane owns cols 2*lane, 2*lane+1.
//   FY via scalar loads (wave-uniform rows, transposed layout), Z coalesced.
// Stage 2: wave w owns out cols 8w..8w+7; lane owns out row n = lane.
//   FX via scalar loads, T rows via ds_read_b64 (stride 130 -> conflict-free).
// ---------------------------------------------------------------------------
__global__ __launch_bounds__(512, 8) void fb_filt(
    const float* __restrict__ x, const float* __restrict__ xh,
    const float* __restrict__ ws, float* __restrict__ out) {
  __shared__ __align__(16) float T[NN * TSTRIDE];  // 33.3 KB

  const int tid = threadIdx.x;
  const int lane = tid & 63;
  const int w8 = __builtin_amdgcn_readfirstlane((tid >> 6) << 3);  // 8*wave, SGPR
  const int bid = blockIdx.x;
  const int k = bid >> 1;
  const int which = bid & 1;
  const float* __restrict__ Z = (which ? xh : x) + (size_t)k * (AB * AB);
  const float* __restrict__ FYt = ws;
  const float* __restrict__ FXt = ws + NN * AB;
  const float gamma = ws[2 * NN * AB];

  // ---- Stage 1: T[8w+j][2lane..2lane+1] = sum_a FYt[a][8w+j] * Z[a][2lane..] ----
  float2 acc[8];
#pragma unroll
  for (int j = 0; j < 8; ++j) acc[j] = make_float2(0.f, 0.f);

  const float2* __restrict__ Zl = (const float2*)Z + lane;
#pragma unroll 4
  for (int a = 0; a < AB; ++a) {
    const float2 z = Zl[a * (AB / 2)];
    const float* __restrict__ fyr = FYt + (a << 6) + w8;  // uniform -> s_load
#pragma unroll
    for (int j = 0; j < 8; ++j) {
      const float f = fyr[j];
      acc[j].x = fmaf(f, z.x, acc[j].x);
      acc[j].y = fmaf(f, z.y, acc[j].y);
    }
  }
#pragma unroll
  for (int j = 0; j < 8; ++j) {
    *(float2*)&T[(w8 + j) * TSTRIDE + (lane << 1)] = acc[j];
  }
  __syncthreads();

  // ---- Stage 2: out[lane][8w+j] = gamma * sum_b T[lane][b] * FXt[b][8w+j] ----
  float acc2[8];
#pragma unroll
  for (int j = 0; j < 8; ++j) acc2[j] = 0.f;

  const float* __restrict__ Trow = &T[lane * TSTRIDE];
#pragma unroll 2
  for (int b = 0; b < AB; b += 2) {
    const float2 t = *(const float2*)&Trow[b];
    const float* __restrict__ fxr = FXt + (b << 6) + w8;   // FXt[b][8w..], uniform
    const float* __restrict__ fxr2 = fxr + NN;             // FXt[b+1][8w..]
#pragma unroll
    for (int j = 0; j < 8; ++j) {
      acc2[j] = fmaf(t.x, fxr[j], fmaf(t.y, fxr2[j], acc2[j]));
    }
  }

  // ---- Epilogue ----
  float* orow = out + (size_t)k * 8192 + which * 4096 + lane * NN + w8;
  *(float4*)(orow + 0) = make_float4(gamma * acc2[0], gamma * acc2[1],
                                     gamma * acc2[2], gamma * acc2[3]);
  *(float4*)(orow + 4) = make_float4(gamma * acc2[4], gamma * acc2[5],
                                     gamma * acc2[6], gamma * acc2[7]);
}

extern "C" void kernel_launch(void* const* d_in, const int* in_sizes, int n_in,
                              void* d_out, int out_size, void* d_ws, size_t ws_size,
                              hipStream_t stream) {
  const float* x = (const float*)d_in[0];
  const float* xh = (const float*)d_in[1];
  const float* h = (const float*)d_in[2];
  const float* Ww = (const float*)d_in[3];
  const float* Wb = (const float*)d_in[4];
  float* ws = (float*)d_ws;
  float* outp = (float*)d_out;

  fb_setup<<<1, 1024, 0, stream>>>(h, Ww, Wb, ws);
  fb_filt<<<2048, 512, 0, stream>>>(x, xh, ws, outp);
}